// Round 1
// baseline (3032.797 us; speedup 1.0000x reference)
//
#include <hip/hip_runtime.h>
#include <cstdint>
#include <cstddef>

#define NN      50000
#define EE      800000
#define NFEATC  512
#define NHID    64
#define NHEADS  8
#define HID_TOT 512   // NHID*NHEADS
#define NCLASS  64
#define ALPHA_LRELU 0.2f

// -------------------- utilities --------------------

__device__ __forceinline__ void atomicMaxF(float* addr, float val) {
    // works for all non-NaN floats when initialized to -inf
    if (val >= 0.0f) atomicMax((int*)addr, __float_as_int(val));
    else             atomicMin((unsigned int*)addr, __float_as_uint(val));
}

__global__ void fill_kernel(float* __restrict__ p, float v, long n) {
    long i = (long)blockIdx.x * blockDim.x + threadIdx.x;
    if (i < n) p[i] = v;
}

// Pack W [NHEADS][NFEAT][NHID] -> Wcat [NFEAT][NHEADS*NHID]
__global__ void pack_w1(const float* __restrict__ W, float* __restrict__ Wcat) {
    int idx = blockIdx.x * 256 + threadIdx.x;
    if (idx >= NFEATC * HID_TOT) return;
    int f = idx >> 9;          // feature
    int c = idx & 511;         // output col = h*64+k
    int h = c >> 6, k = c & 63;
    Wcat[idx] = W[(h << 15) + (f << 6) + k];   // h*512*64 + f*64 + k
}

// -------------------- f32 GEMM: C[M,N] = A[M,K] @ B[K,N] --------------------
// 64x64 tile, 256 threads, 4x4 micro-tile, K-tile 16.
__global__ __launch_bounds__(256) void gemm64(const float* __restrict__ A,
                                              const float* __restrict__ B,
                                              float* __restrict__ C,
                                              int M, int N, int K) {
    __shared__ float As[16][65];
    __shared__ float Bs[16][65];
    const int bm = blockIdx.y * 64;
    const int bn = blockIdx.x * 64;
    const int tid = threadIdx.x;
    const int tx = tid & 15;     // col group
    const int ty = tid >> 4;     // row group
    float acc[4][4] = {};
    for (int k0 = 0; k0 < K; k0 += 16) {
        // A tile: 64 rows x 16 k
        #pragma unroll
        for (int i = tid; i < 64 * 16; i += 256) {
            int m = i >> 4, kk = i & 15;
            int gr = bm + m;
            As[kk][m] = (gr < M) ? A[(size_t)gr * K + k0 + kk] : 0.0f;
        }
        // B tile: 16 k x 64 cols (N is always a multiple of 64 here)
        #pragma unroll
        for (int i = tid; i < 16 * 64; i += 256) {
            int kk = i >> 6, n = i & 63;
            Bs[kk][n] = B[(size_t)(k0 + kk) * N + bn + n];
        }
        __syncthreads();
        #pragma unroll
        for (int kk = 0; kk < 16; ++kk) {
            float a[4], b[4];
            #pragma unroll
            for (int i = 0; i < 4; i++) a[i] = As[kk][ty * 4 + i];
            #pragma unroll
            for (int j = 0; j < 4; j++) b[j] = Bs[kk][tx * 4 + j];
            #pragma unroll
            for (int i = 0; i < 4; i++)
                #pragma unroll
                for (int j = 0; j < 4; j++) acc[i][j] += a[i] * b[j];
        }
        __syncthreads();
    }
    #pragma unroll
    for (int i = 0; i < 4; i++) {
        int gr = bm + ty * 4 + i;
        if (gr < M) {
            #pragma unroll
            for (int j = 0; j < 4; j++)
                C[(size_t)gr * N + bn + tx * 4 + j] = acc[i][j];
        }
    }
}

// -------------------- layer 1 attention pieces --------------------

// fd[n,h] = dot(Wh[n, h*64 : h*64+64], a[h, 0:64]); fs likewise with a[h,64:128]
__global__ void dots1(const float* __restrict__ Wh, const float* __restrict__ a,
                      float* __restrict__ fd, float* __restrict__ fs) {
    int idx = blockIdx.x * 256 + threadIdx.x;
    if (idx >= NN * NHEADS) return;
    int n = idx >> 3, h = idx & 7;
    const float* w = Wh + (size_t)n * HID_TOT + h * NHID;
    const float* ad = a + h * 2 * NHID;
    float sd = 0.f, ss = 0.f;
    #pragma unroll
    for (int k = 0; k < NHID; k++) {
        float v = w[k];
        sd += v * ad[k];
        ss += v * ad[NHID + k];
    }
    fd[idx] = sd;
    fs[idx] = ss;
}

__global__ void edgemax1(const int* __restrict__ row, const int* __restrict__ col,
                         const float* __restrict__ fd, const float* __restrict__ fs,
                         float* __restrict__ m) {
    long idx = (long)blockIdx.x * 256 + threadIdx.x;   // (e,h)
    if (idx >= (long)EE * NHEADS) return;
    int e = (int)(idx >> 3), h = (int)(idx & 7);
    int i = row[e], j = col[e];
    float v = fd[i * 8 + h] + fs[j * 8 + h];
    v = v > 0.f ? v : ALPHA_LRELU * v;
    atomicMaxF(&m[i * 8 + h], v);
}

// one wave per (edge, head): 64 lanes cover the 64 hidden dims
__global__ __launch_bounds__(256) void agg1_k(const int* __restrict__ row, const int* __restrict__ col,
                                              const float* __restrict__ fd, const float* __restrict__ fs,
                                              const float* __restrict__ m, const float* __restrict__ Wh,
                                              float* __restrict__ agg, float* __restrict__ denom) {
    long wid = (long)blockIdx.x * 4 + (threadIdx.x >> 6);
    int lane = threadIdx.x & 63;
    if (wid >= (long)EE * NHEADS) return;
    int e = (int)(wid >> 3), h = (int)(wid & 7);
    int i = row[e], j = col[e];
    float v = fd[i * 8 + h] + fs[j * 8 + h];
    v = v > 0.f ? v : ALPHA_LRELU * v;
    float p = __expf(v - m[i * 8 + h]);
    if (lane == 0) atomicAdd(&denom[i * 8 + h], p);
    float w = Wh[(size_t)j * HID_TOT + h * NHID + lane];
    atomicAdd(&agg[(size_t)i * HID_TOT + h * NHID + lane], p * w);
}

// h1 = elu(agg / max(denom,1e-16)), in place
__global__ void finalize1(float* __restrict__ agg, const float* __restrict__ denom) {
    long idx = (long)blockIdx.x * 256 + threadIdx.x;
    if (idx >= (long)NN * HID_TOT) return;
    int n = (int)(idx >> 9);
    int hk = (int)(idx & 511);
    int h = hk >> 6;
    float d = denom[n * 8 + h];
    float v = agg[idx] / fmaxf(d, 1e-16f);
    agg[idx] = v > 0.f ? v : (expf(v) - 1.0f);
}

// -------------------- layer 2 attention pieces --------------------

__global__ void dots2(const float* __restrict__ Wh2, const float* __restrict__ a_out,
                      float* __restrict__ fd, float* __restrict__ fs) {
    int n = blockIdx.x * 256 + threadIdx.x;
    if (n >= NN) return;
    const float* w = Wh2 + (size_t)n * NCLASS;
    float sd = 0.f, ss = 0.f;
    #pragma unroll
    for (int k = 0; k < NCLASS; k++) {
        float v = w[k];
        sd += v * a_out[k];
        ss += v * a_out[NCLASS + k];
    }
    fd[n] = sd;
    fs[n] = ss;
}

__global__ void edgemax2(const int* __restrict__ row, const int* __restrict__ col,
                         const float* __restrict__ fd, const float* __restrict__ fs,
                         float* __restrict__ m) {
    int e = blockIdx.x * 256 + threadIdx.x;
    if (e >= EE) return;
    int i = row[e], j = col[e];
    float v = fd[i] + fs[j];
    v = v > 0.f ? v : ALPHA_LRELU * v;
    atomicMaxF(&m[i], v);
}

// one wave per edge
__global__ __launch_bounds__(256) void agg2_k(const int* __restrict__ row, const int* __restrict__ col,
                                              const float* __restrict__ fd, const float* __restrict__ fs,
                                              const float* __restrict__ m, const float* __restrict__ Wh2,
                                              float* __restrict__ out, float* __restrict__ denom) {
    long wid = (long)blockIdx.x * 4 + (threadIdx.x >> 6);
    int lane = threadIdx.x & 63;
    if (wid >= EE) return;
    int e = (int)wid;
    int i = row[e], j = col[e];
    float v = fd[i] + fs[j];
    v = v > 0.f ? v : ALPHA_LRELU * v;
    float p = __expf(v - m[i]);
    if (lane == 0) atomicAdd(&denom[i], p);
    float w = Wh2[(size_t)j * NCLASS + lane];
    atomicAdd(&out[(size_t)i * NCLASS + lane], p * w);
}

__global__ void finalize2(float* __restrict__ out, const float* __restrict__ denom) {
    long idx = (long)blockIdx.x * 256 + threadIdx.x;
    if (idx >= (long)NN * NCLASS) return;
    int n = (int)(idx >> 6);
    out[idx] = out[idx] / fmaxf(denom[n], 1e-16f);
}

// -------------------- launch --------------------

static inline int cdiv_l(long a, long b) { return (int)((a + b - 1) / b); }

extern "C" void kernel_launch(void* const* d_in, const int* in_sizes, int n_in,
                              void* d_out, int out_size, void* d_ws, size_t ws_size,
                              hipStream_t stream) {
    const float* x     = (const float*)d_in[0];
    const int*   row   = (const int*)d_in[1];
    const int*   col   = (const int*)d_in[2];
    const float* W     = (const float*)d_in[3];
    const float* a     = (const float*)d_in[4];
    const float* W_out = (const float*)d_in[5];
    const float* a_out = (const float*)d_in[6];
    float* out = (float*)d_out;

    // workspace layout (floats)
    float* ws = (float*)d_ws;
    size_t off = 0;
    float* Wcat1  = ws + off; off += (size_t)NFEATC * HID_TOT;   // 262144
    float* Wh1    = ws + off; off += (size_t)NN * HID_TOT;       // 25.6M
    float* fd1    = ws + off; off += (size_t)NN * NHEADS;
    float* fs1    = ws + off; off += (size_t)NN * NHEADS;
    float* m1     = ws + off; off += (size_t)NN * NHEADS;
    float* den1   = ws + off; off += (size_t)NN * NHEADS;
    float* Wh2    = ws + off; off += (size_t)NN * NCLASS;        // 3.2M
    float* fd2    = ws + off; off += (size_t)NN;
    float* fs2    = ws + off; off += (size_t)NN;
    float* m2     = ws + off; off += (size_t)NN;
    float* den2   = ws + off; off += (size_t)NN;
    float* agg1   = ws + off; off += (size_t)NN * HID_TOT;       // 25.6M (becomes h1 in place)

    const float NEG_INF = -__builtin_huge_valf();

    // ---- layer 1 ----
    pack_w1<<<cdiv_l((long)NFEATC * HID_TOT, 256), 256, 0, stream>>>(W, Wcat1);
    {
        dim3 grid(HID_TOT / 64, cdiv_l(NN, 64));
        gemm64<<<grid, 256, 0, stream>>>(x, Wcat1, Wh1, NN, HID_TOT, NFEATC);
    }
    dots1<<<cdiv_l((long)NN * NHEADS, 256), 256, 0, stream>>>(Wh1, a, fd1, fs1);

    fill_kernel<<<cdiv_l((long)NN * NHEADS, 256), 256, 0, stream>>>(m1, NEG_INF, (long)NN * NHEADS);
    fill_kernel<<<cdiv_l((long)NN * NHEADS, 256), 256, 0, stream>>>(den1, 0.0f, (long)NN * NHEADS);
    fill_kernel<<<cdiv_l((long)NN * HID_TOT, 256), 256, 0, stream>>>(agg1, 0.0f, (long)NN * HID_TOT);

    edgemax1<<<cdiv_l((long)EE * NHEADS, 256), 256, 0, stream>>>(row, col, fd1, fs1, m1);
    agg1_k<<<cdiv_l((long)EE * NHEADS, 4), 256, 0, stream>>>(row, col, fd1, fs1, m1, Wh1, agg1, den1);
    finalize1<<<cdiv_l((long)NN * HID_TOT, 256), 256, 0, stream>>>(agg1, den1);

    // ---- layer 2 ----  (agg1 now holds h1 [NN, 512])
    {
        dim3 grid(NCLASS / 64, cdiv_l(NN, 64));
        gemm64<<<grid, 256, 0, stream>>>(agg1, W_out, Wh2, NN, NCLASS, NFEATC);
    }
    dots2<<<cdiv_l(NN, 256), 256, 0, stream>>>(Wh2, a_out, fd2, fs2);

    fill_kernel<<<cdiv_l(NN, 256), 256, 0, stream>>>(m2, NEG_INF, (long)NN);
    fill_kernel<<<cdiv_l(NN, 256), 256, 0, stream>>>(den2, 0.0f, (long)NN);
    fill_kernel<<<cdiv_l((long)NN * NCLASS, 256), 256, 0, stream>>>(out, 0.0f, (long)NN * NCLASS);

    edgemax2<<<cdiv_l(EE, 256), 256, 0, stream>>>(row, col, fd2, fs2, m2);
    agg2_k<<<cdiv_l(EE, 4), 256, 0, stream>>>(row, col, fd2, fs2, m2, Wh2, out, den2);
    finalize2<<<cdiv_l((long)NN * NCLASS, 256), 256, 0, stream>>>(out, den2);
}

// Round 2
// 1527.513 us; speedup vs baseline: 1.9854x; 1.9854x over previous
//
#include <hip/hip_runtime.h>
#include <cstdint>
#include <cstddef>

#define NN      50000
#define EE      800000
#define NFEATC  512
#define NHID    64
#define NHEADS  8
#define HID_TOT 512   // NHID*NHEADS
#define NCLASS  64
#define ALPHA_LRELU 0.2f

// -------------------- small utilities --------------------

__global__ void fill_i32(int* __restrict__ p, int v, long n) {
    long i = (long)blockIdx.x * blockDim.x + threadIdx.x;
    if (i < n) p[i] = v;
}

// Pack W [NHEADS][NFEAT][NHID] -> Wcat [NFEAT][NHEADS*NHID]
__global__ void pack_w1(const float* __restrict__ W, float* __restrict__ Wcat) {
    int idx = blockIdx.x * 256 + threadIdx.x;
    if (idx >= NFEATC * HID_TOT) return;
    int f = idx >> 9;          // feature
    int c = idx & 511;         // output col = h*64+k
    int h = c >> 6, k = c & 63;
    Wcat[idx] = W[(h << 15) + (f << 6) + k];   // h*512*64 + f*64 + k
}

// -------------------- CSR build --------------------

__global__ void hist_rows(const int* __restrict__ row, int* __restrict__ cnt) {
    int e = blockIdx.x * 256 + threadIdx.x;
    if (e >= EE) return;
    atomicAdd(&cnt[row[e]], 1);
}

// single-block exclusive scan of cnt[0..NN) -> start[0..NN], also copy to wr
__global__ __launch_bounds__(1024) void scan_nodes(const int* __restrict__ cnt,
                                                   int* __restrict__ start,
                                                   int* __restrict__ wr) {
    __shared__ int part[1024];
    const int tid = threadIdx.x;
    const int CH = (NN + 1023) / 1024;   // 49
    const int base = tid * CH;
    int s = 0;
    for (int k = 0; k < CH; k++) {
        int idx = base + k;
        if (idx < NN) s += cnt[idx];
    }
    part[tid] = s;
    __syncthreads();
    for (int off = 1; off < 1024; off <<= 1) {
        int v = part[tid];
        int add = (tid >= off) ? part[tid - off] : 0;
        __syncthreads();
        part[tid] = v + add;
        __syncthreads();
    }
    int excl = (tid == 0) ? 0 : part[tid - 1];
    for (int k = 0; k < CH; k++) {
        int idx = base + k;
        if (idx < NN) {
            start[idx] = excl;
            wr[idx] = excl;
            excl += cnt[idx];
        }
    }
    if (tid == 0) start[NN] = EE;
}

// scatter source node ids into dest-sorted order
__global__ void scatter_edges(const int* __restrict__ row, const int* __restrict__ col,
                              int* __restrict__ wr, int* __restrict__ ecol) {
    int e = blockIdx.x * 256 + threadIdx.x;
    if (e >= EE) return;
    int i = row[e];
    int pos = atomicAdd(&wr[i], 1);
    ecol[pos] = col[e];
}

// -------------------- f32 GEMM: C[M,N] = A[M,K] @ B[K,N] --------------------
__global__ __launch_bounds__(256) void gemm64(const float* __restrict__ A,
                                              const float* __restrict__ B,
                                              float* __restrict__ C,
                                              int M, int N, int K) {
    __shared__ float As[16][65];
    __shared__ float Bs[16][65];
    const int bm = blockIdx.y * 64;
    const int bn = blockIdx.x * 64;
    const int tid = threadIdx.x;
    const int tx = tid & 15;
    const int ty = tid >> 4;
    float acc[4][4] = {};
    for (int k0 = 0; k0 < K; k0 += 16) {
        #pragma unroll
        for (int i = tid; i < 64 * 16; i += 256) {
            int m = i >> 4, kk = i & 15;
            int gr = bm + m;
            As[kk][m] = (gr < M) ? A[(size_t)gr * K + k0 + kk] : 0.0f;
        }
        #pragma unroll
        for (int i = tid; i < 16 * 64; i += 256) {
            int kk = i >> 6, n = i & 63;
            Bs[kk][n] = B[(size_t)(k0 + kk) * N + bn + n];
        }
        __syncthreads();
        #pragma unroll
        for (int kk = 0; kk < 16; ++kk) {
            float a[4], b[4];
            #pragma unroll
            for (int i = 0; i < 4; i++) a[i] = As[kk][ty * 4 + i];
            #pragma unroll
            for (int j = 0; j < 4; j++) b[j] = Bs[kk][tx * 4 + j];
            #pragma unroll
            for (int i = 0; i < 4; i++)
                #pragma unroll
                for (int j = 0; j < 4; j++) acc[i][j] += a[i] * b[j];
        }
        __syncthreads();
    }
    #pragma unroll
    for (int i = 0; i < 4; i++) {
        int gr = bm + ty * 4 + i;
        if (gr < M) {
            #pragma unroll
            for (int j = 0; j < 4; j++)
                C[(size_t)gr * N + bn + tx * 4 + j] = acc[i][j];
        }
    }
}

// -------------------- attention dot products --------------------

__global__ void dots1(const float* __restrict__ Wh, const float* __restrict__ a,
                      float* __restrict__ fd, float* __restrict__ fs) {
    int idx = blockIdx.x * 256 + threadIdx.x;
    if (idx >= NN * NHEADS) return;
    int n = idx >> 3, h = idx & 7;
    const float* w = Wh + (size_t)n * HID_TOT + h * NHID;
    const float* ad = a + h * 2 * NHID;
    float sd = 0.f, ss = 0.f;
    #pragma unroll
    for (int k = 0; k < NHID; k++) {
        float v = w[k];
        sd += v * ad[k];
        ss += v * ad[NHID + k];
    }
    fd[idx] = sd;
    fs[idx] = ss;
}

__global__ void dots2(const float* __restrict__ Wh2, const float* __restrict__ a_out,
                      float* __restrict__ fd, float* __restrict__ fs) {
    int n = blockIdx.x * 256 + threadIdx.x;
    if (n >= NN) return;
    const float* w = Wh2 + (size_t)n * NCLASS;
    float sd = 0.f, ss = 0.f;
    #pragma unroll
    for (int k = 0; k < NCLASS; k++) {
        float v = w[k];
        sd += v * a_out[k];
        ss += v * a_out[NCLASS + k];
    }
    fd[n] = sd;
    fs[n] = ss;
}

// -------------------- CSR segment-softmax aggregation --------------------
// layer 1: block = 512 threads = 8 waves; block b = node b; wave h = head h.
__global__ __launch_bounds__(512) void agg1_csr(const int* __restrict__ start,
                                                const int* __restrict__ ecol,
                                                const float* __restrict__ fd,
                                                const float* __restrict__ fs,
                                                const float* __restrict__ Wh,
                                                float* __restrict__ h1) {
    const int i = blockIdx.x;
    const int h = threadIdx.x >> 6;
    const int lane = threadIdx.x & 63;
    const int s = start[i], e = start[i + 1];
    const float fdv = fd[i * 8 + h];

    // pass 1: max over edges (edges distributed over lanes)
    float m = -__builtin_huge_valf();
    for (int t = s + lane; t < e; t += 64) {
        int j = ecol[t];
        float v = fdv + fs[j * 8 + h];
        v = v > 0.f ? v : ALPHA_LRELU * v;
        m = fmaxf(m, v);
    }
    #pragma unroll
    for (int o = 32; o; o >>= 1) m = fmaxf(m, __shfl_xor(m, o));

    // pass 2: weighted accumulate; lane covers hidden dim
    float acc = 0.f, den = 0.f;
    for (int t = s; t < e; ++t) {
        int j = ecol[t];                       // broadcast load
        float v = fdv + fs[j * 8 + h];         // broadcast load
        v = v > 0.f ? v : ALPHA_LRELU * v;
        float p = __expf(v - m);
        den += p;
        acc += p * Wh[(size_t)j * HID_TOT + h * NHID + lane];
    }
    float o = acc / fmaxf(den, 1e-16f);
    h1[(size_t)i * HID_TOT + h * NHID + lane] = o > 0.f ? o : (__expf(o) - 1.0f);
}

// layer 2: 4 waves / block, wave = node; lane covers NCLASS
__global__ __launch_bounds__(256) void agg2_csr(const int* __restrict__ start,
                                                const int* __restrict__ ecol,
                                                const float* __restrict__ fd,
                                                const float* __restrict__ fs,
                                                const float* __restrict__ Wh2,
                                                float* __restrict__ out) {
    const int i = blockIdx.x * 4 + (threadIdx.x >> 6);
    if (i >= NN) return;
    const int lane = threadIdx.x & 63;
    const int s = start[i], e = start[i + 1];
    const float fdv = fd[i];

    float m = -__builtin_huge_valf();
    for (int t = s + lane; t < e; t += 64) {
        int j = ecol[t];
        float v = fdv + fs[j];
        v = v > 0.f ? v : ALPHA_LRELU * v;
        m = fmaxf(m, v);
    }
    #pragma unroll
    for (int o = 32; o; o >>= 1) m = fmaxf(m, __shfl_xor(m, o));

    float acc = 0.f, den = 0.f;
    for (int t = s; t < e; ++t) {
        int j = ecol[t];
        float v = fdv + fs[j];
        v = v > 0.f ? v : ALPHA_LRELU * v;
        float p = __expf(v - m);
        den += p;
        acc += p * Wh2[(size_t)j * NCLASS + lane];
    }
    out[(size_t)i * NCLASS + lane] = acc / fmaxf(den, 1e-16f);
}

// -------------------- launch --------------------

static inline int cdiv_l(long a, long b) { return (int)((a + b - 1) / b); }

extern "C" void kernel_launch(void* const* d_in, const int* in_sizes, int n_in,
                              void* d_out, int out_size, void* d_ws, size_t ws_size,
                              hipStream_t stream) {
    const float* x     = (const float*)d_in[0];
    const int*   row   = (const int*)d_in[1];
    const int*   col   = (const int*)d_in[2];
    const float* W     = (const float*)d_in[3];
    const float* a     = (const float*)d_in[4];
    const float* W_out = (const float*)d_in[5];
    const float* a_out = (const float*)d_in[6];
    float* out = (float*)d_out;

    // workspace layout (floats / ints)
    float* ws = (float*)d_ws;
    size_t off = 0;
    float* Wcat1  = ws + off; off += (size_t)NFEATC * HID_TOT;   // 262144
    float* Wh1    = ws + off; off += (size_t)NN * HID_TOT;       // 25.6M
    float* fd1    = ws + off; off += (size_t)NN * NHEADS;
    float* fs1    = ws + off; off += (size_t)NN * NHEADS;
    float* Wh2    = ws + off; off += (size_t)NN * NCLASS;        // 3.2M
    float* fd2    = ws + off; off += (size_t)NN;
    float* fs2    = ws + off; off += (size_t)NN;
    float* h1     = ws + off; off += (size_t)NN * HID_TOT;       // 25.6M
    int*   cnt    = (int*)(ws + off); off += (size_t)NN;
    int*   startp = (int*)(ws + off); off += (size_t)NN + 1;
    int*   wr     = (int*)(ws + off); off += (size_t)NN;
    int*   ecol   = (int*)(ws + off); off += (size_t)EE;

    // ---- CSR build (shared by both layers) ----
    fill_i32<<<cdiv_l(NN, 256), 256, 0, stream>>>(cnt, 0, (long)NN);
    hist_rows<<<cdiv_l(EE, 256), 256, 0, stream>>>(row, cnt);
    scan_nodes<<<1, 1024, 0, stream>>>(cnt, startp, wr);
    scatter_edges<<<cdiv_l(EE, 256), 256, 0, stream>>>(row, col, wr, ecol);

    // ---- layer 1 ----
    pack_w1<<<cdiv_l((long)NFEATC * HID_TOT, 256), 256, 0, stream>>>(W, Wcat1);
    {
        dim3 grid(HID_TOT / 64, cdiv_l(NN, 64));
        gemm64<<<grid, 256, 0, stream>>>(x, Wcat1, Wh1, NN, HID_TOT, NFEATC);
    }
    dots1<<<cdiv_l((long)NN * NHEADS, 256), 256, 0, stream>>>(Wh1, a, fd1, fs1);
    agg1_csr<<<NN, 512, 0, stream>>>(startp, ecol, fd1, fs1, Wh1, h1);

    // ---- layer 2 ----
    {
        dim3 grid(NCLASS / 64, cdiv_l(NN, 64));
        gemm64<<<grid, 256, 0, stream>>>(h1, W_out, Wh2, NN, NCLASS, NFEATC);
    }
    dots2<<<cdiv_l(NN, 256), 256, 0, stream>>>(Wh2, a_out, fd2, fs2);
    agg2_csr<<<cdiv_l(NN, 4), 256, 0, stream>>>(startp, ecol, fd2, fs2, Wh2, out);
}

// Round 3
// 932.529 us; speedup vs baseline: 3.2522x; 1.6380x over previous
//
#include <hip/hip_runtime.h>
#include <cstdint>
#include <cstddef>

#define NN      50000
#define MPAD    50048   // NN padded to 128
#define EE      800000
#define NFEATC  512
#define NHID    64
#define NHEADS  8
#define HID_TOT 512
#define NCLASS  64
#define ALPHA_LRELU 0.2f

typedef unsigned short u16;

__device__ __forceinline__ float bf2f(u16 v) {
    return __uint_as_float(((unsigned)v) << 16);
}
__device__ __forceinline__ u16 f2bf(float f) {   // round-to-nearest-even
    unsigned u = __float_as_uint(f);
    return (u16)((u + 0x7fffu + ((u >> 16) & 1u)) >> 16);
}

// -------------------- small utilities --------------------

__global__ void fill_i32(int* __restrict__ p, int v, long n) {
    long i = (long)blockIdx.x * blockDim.x + threadIdx.x;
    if (i < n) p[i] = v;
}
__global__ void fill_u16(u16* __restrict__ p, u16 v, long n) {
    long i = (long)blockIdx.x * blockDim.x + threadIdx.x;
    if (i < n) p[i] = v;
}

// cast x [NN,512] f32 -> xb [MPAD,512] bf16, zero pad rows. 4 elems/thread.
__global__ void cast_x(const float* __restrict__ x, u16* __restrict__ xb) {
    int g = blockIdx.x * 256 + threadIdx.x;
    if (g >= MPAD * 128) return;           // 128 groups of 4 per row
    int r = g >> 7;
    int c = (g & 127) * 4;
    u16 o0 = 0, o1 = 0, o2 = 0, o3 = 0;
    if (r < NN) {
        const float4 v = *(const float4*)(x + (size_t)r * 512 + c);
        o0 = f2bf(v.x); o1 = f2bf(v.y); o2 = f2bf(v.z); o3 = f2bf(v.w);
    }
    u16* d = xb + (size_t)r * 512 + c;
    d[0] = o0; d[1] = o1; d[2] = o2; d[3] = o3;
}

// W [8][512][64] f32 -> Wcat_t [512(N=h*64+j)][512(K=f)] bf16 (B^T layout)
__global__ void pack_w1t(const float* __restrict__ W, u16* __restrict__ Wt) {
    int idx = blockIdx.x * 256 + threadIdx.x;
    if (idx >= 512 * 512) return;
    int c = idx >> 9, f = idx & 511;       // c = output col, f = feature (K)
    int h = c >> 6, j = c & 63;
    Wt[idx] = f2bf(W[(h << 15) + (f << 6) + j]);
}

// W_out [512][64] f32 -> Wot_t [64(N)][512(K)] bf16
__global__ void pack_woutt(const float* __restrict__ W, u16* __restrict__ Wt) {
    int idx = blockIdx.x * 256 + threadIdx.x;
    if (idx >= 64 * 512) return;
    int n = idx >> 9, k = idx & 511;
    Wt[idx] = f2bf(W[k * 64 + n]);
}

// -------------------- CSR build --------------------

__global__ void hist_rows(const int* __restrict__ row, int* __restrict__ cnt) {
    int e = blockIdx.x * 256 + threadIdx.x;
    if (e >= EE) return;
    atomicAdd(&cnt[row[e]], 1);
}

__global__ __launch_bounds__(1024) void scan_nodes(const int* __restrict__ cnt,
                                                   int* __restrict__ start,
                                                   int* __restrict__ wr) {
    __shared__ int part[1024];
    const int tid = threadIdx.x;
    const int CH = (NN + 1023) / 1024;
    const int base = tid * CH;
    int s = 0;
    for (int k = 0; k < CH; k++) {
        int idx = base + k;
        if (idx < NN) s += cnt[idx];
    }
    part[tid] = s;
    __syncthreads();
    for (int off = 1; off < 1024; off <<= 1) {
        int v = part[tid];
        int add = (tid >= off) ? part[tid - off] : 0;
        __syncthreads();
        part[tid] = v + add;
        __syncthreads();
    }
    int excl = (tid == 0) ? 0 : part[tid - 1];
    for (int k = 0; k < CH; k++) {
        int idx = base + k;
        if (idx < NN) {
            start[idx] = excl;
            wr[idx] = excl;
            excl += cnt[idx];
        }
    }
    if (tid == 0) start[NN] = EE;
}

__global__ void scatter_edges(const int* __restrict__ row, const int* __restrict__ col,
                              int* __restrict__ wr, int* __restrict__ ecol) {
    int e = blockIdx.x * 256 + threadIdx.x;
    if (e >= EE) return;
    int i = row[e];
    int pos = atomicAdd(&wr[i], 1);
    ecol[pos] = col[e];
}

// -------------------- bf16 MFMA GEMM --------------------
// C[M,N] = A[M,K](bf16, M padded to 128) @ Bt[N,K]^T (bf16).
// BM=128, BK=32, 256 threads (2x2 waves), per-wave 4 x NT tiles of 16x16.

__device__ __forceinline__ void load_lds_128(const u16* g, u16* l) {
    __builtin_amdgcn_global_load_lds((const __attribute__((address_space(1))) void*)g,
                                     (__attribute__((address_space(3))) void*)l,
                                     16, 0, 0);
}

typedef __attribute__((ext_vector_type(8))) short frag8;
typedef __attribute__((ext_vector_type(4))) float f32x4;

template <int BN, bool OUT_BF16>
__global__ __launch_bounds__(256) void gemm_bf16(const u16* __restrict__ A,
                                                 const u16* __restrict__ Bt,
                                                 void* __restrict__ Cv,
                                                 int M, int N, int K) {
    constexpr int BM = 128, BK = 32;
    constexpr int WN = BN / 2;
    constexpr int NT = WN / 16;
    __shared__ u16 As[BM * BK];
    __shared__ u16 Bs[BN * BK];
    const int tid = threadIdx.x;
    const int wave = tid >> 6, lane = tid & 63;
    const int wm = wave & 1, wn = wave >> 1;
    const int bm = blockIdx.y * BM, bn = blockIdx.x * BN;
    const int q = lane >> 4, lr = lane & 15;

    f32x4 acc[4][NT] = {};

    for (int k0 = 0; k0 < K; k0 += BK) {
        #pragma unroll
        for (int c = wave; c < (BM * BK) / 512; c += 4) {
            int f = c * 512 + lane * 8;
            int row = f >> 5, ck = f & 31;
            load_lds_128(A + (size_t)(bm + row) * K + k0 + ck, As + c * 512);
        }
        #pragma unroll
        for (int c = wave; c < (BN * BK) / 512; c += 4) {
            int f = c * 512 + lane * 8;
            int row = f >> 5, ck = f & 31;
            load_lds_128(Bt + (size_t)(bn + row) * K + k0 + ck, Bs + c * 512);
        }
        __syncthreads();
        frag8 af[4], bfr[NT];
        #pragma unroll
        for (int am = 0; am < 4; am++)
            af[am] = *(const frag8*)(As + (wm * 64 + am * 16 + lr) * 32 + q * 8);
        #pragma unroll
        for (int bt = 0; bt < NT; bt++)
            bfr[bt] = *(const frag8*)(Bs + (wn * WN + bt * 16 + lr) * 32 + q * 8);
        #pragma unroll
        for (int am = 0; am < 4; am++)
            #pragma unroll
            for (int bt = 0; bt < NT; bt++)
                acc[am][bt] = __builtin_amdgcn_mfma_f32_16x16x32_bf16(af[am], bfr[bt], acc[am][bt], 0, 0, 0);
        __syncthreads();
    }

    #pragma unroll
    for (int am = 0; am < 4; am++) {
        #pragma unroll
        for (int reg = 0; reg < 4; reg++) {
            int gr = bm + wm * 64 + am * 16 + q * 4 + reg;
            if (gr < M) {
                #pragma unroll
                for (int bt = 0; bt < NT; bt++) {
                    int gc = bn + wn * WN + bt * 16 + lr;
                    float v = acc[am][bt][reg];
                    if (OUT_BF16) ((u16*)Cv)[(size_t)gr * N + gc] = f2bf(v);
                    else          ((float*)Cv)[(size_t)gr * N + gc] = v;
                }
            }
        }
    }
}

// -------------------- attention dot products --------------------

__global__ void dots1(const u16* __restrict__ Wh, const float* __restrict__ a,
                      float* __restrict__ fd, float* __restrict__ fs) {
    int idx = blockIdx.x * 256 + threadIdx.x;
    if (idx >= NN * NHEADS) return;
    int n = idx >> 3, h = idx & 7;
    const u16* w = Wh + (size_t)n * HID_TOT + h * NHID;
    const float* ad = a + h * 2 * NHID;
    float sd = 0.f, ss = 0.f;
    #pragma unroll
    for (int k = 0; k < NHID; k++) {
        float v = bf2f(w[k]);
        sd += v * ad[k];
        ss += v * ad[NHID + k];
    }
    fd[idx] = sd;
    fs[idx] = ss;
}

__global__ void dots2(const float* __restrict__ Wh2, const float* __restrict__ a_out,
                      float* __restrict__ fd, float* __restrict__ fs) {
    int n = blockIdx.x * 256 + threadIdx.x;
    if (n >= NN) return;
    const float* w = Wh2 + (size_t)n * NCLASS;
    float sd = 0.f, ss = 0.f;
    #pragma unroll
    for (int k = 0; k < NCLASS; k++) {
        float v = w[k];
        sd += v * a_out[k];
        ss += v * a_out[NCLASS + k];
    }
    fd[n] = sd;
    fs[n] = ss;
}

// -------------------- CSR segment-softmax aggregation --------------------

__global__ __launch_bounds__(512) void agg1_csr(const int* __restrict__ start,
                                                const int* __restrict__ ecol,
                                                const float* __restrict__ fd,
                                                const float* __restrict__ fs,
                                                const u16* __restrict__ Whb,
                                                u16* __restrict__ h1b) {
    const int i = blockIdx.x;
    const int h = threadIdx.x >> 6;
    const int lane = threadIdx.x & 63;
    const int s = start[i], e = start[i + 1];
    const float fdv = fd[i * 8 + h];

    float m = -__builtin_huge_valf();
    for (int t = s + lane; t < e; t += 64) {
        int j = ecol[t];
        float v = fdv + fs[j * 8 + h];
        v = v > 0.f ? v : ALPHA_LRELU * v;
        m = fmaxf(m, v);
    }
    #pragma unroll
    for (int o = 32; o; o >>= 1) m = fmaxf(m, __shfl_xor(m, o));

    float acc = 0.f, den = 0.f;
    for (int t = s; t < e; ++t) {
        int j = ecol[t];
        float v = fdv + fs[j * 8 + h];
        v = v > 0.f ? v : ALPHA_LRELU * v;
        float p = __expf(v - m);
        den += p;
        acc += p * bf2f(Whb[(size_t)j * HID_TOT + h * NHID + lane]);
    }
    float o = acc / fmaxf(den, 1e-16f);
    o = o > 0.f ? o : (__expf(o) - 1.0f);
    h1b[(size_t)i * HID_TOT + h * NHID + lane] = f2bf(o);
}

__global__ __launch_bounds__(256) void agg2_csr(const int* __restrict__ start,
                                                const int* __restrict__ ecol,
                                                const float* __restrict__ fd,
                                                const float* __restrict__ fs,
                                                const float* __restrict__ Wh2,
                                                float* __restrict__ out) {
    const int i = blockIdx.x * 4 + (threadIdx.x >> 6);
    if (i >= NN) return;
    const int lane = threadIdx.x & 63;
    const int s = start[i], e = start[i + 1];
    const float fdv = fd[i];

    float m = -__builtin_huge_valf();
    for (int t = s + lane; t < e; t += 64) {
        int j = ecol[t];
        float v = fdv + fs[j];
        v = v > 0.f ? v : ALPHA_LRELU * v;
        m = fmaxf(m, v);
    }
    #pragma unroll
    for (int o = 32; o; o >>= 1) m = fmaxf(m, __shfl_xor(m, o));

    float acc = 0.f, den = 0.f;
    for (int t = s; t < e; ++t) {
        int j = ecol[t];
        float v = fdv + fs[j];
        v = v > 0.f ? v : ALPHA_LRELU * v;
        float p = __expf(v - m);
        den += p;
        acc += p * Wh2[(size_t)j * NCLASS + lane];
    }
    out[(size_t)i * NCLASS + lane] = acc / fmaxf(den, 1e-16f);
}

// -------------------- launch --------------------

static inline int cdiv_l(long a, long b) { return (int)((a + b - 1) / b); }

extern "C" void kernel_launch(void* const* d_in, const int* in_sizes, int n_in,
                              void* d_out, int out_size, void* d_ws, size_t ws_size,
                              hipStream_t stream) {
    const float* x     = (const float*)d_in[0];
    const int*   row   = (const int*)d_in[1];
    const int*   col   = (const int*)d_in[2];
    const float* W     = (const float*)d_in[3];
    const float* a     = (const float*)d_in[4];
    const float* W_out = (const float*)d_in[5];
    const float* a_out = (const float*)d_in[6];
    float* out = (float*)d_out;

    // workspace layout (byte offsets, 256B aligned chunks)
    char* wsb = (char*)d_ws;
    size_t off = 0;
    auto alloc = [&](size_t bytes) { char* p = wsb + off; off += (bytes + 255) & ~(size_t)255; return p; };
    u16*   xb     = (u16*)  alloc((size_t)MPAD * 512 * 2);
    u16*   Wcat_t = (u16*)  alloc((size_t)512 * 512 * 2);
    u16*   Wot_t  = (u16*)  alloc((size_t)64 * 512 * 2);
    u16*   Whb1   = (u16*)  alloc((size_t)NN * 512 * 2);
    float* fd1    = (float*)alloc((size_t)NN * 8 * 4);
    float* fs1    = (float*)alloc((size_t)NN * 8 * 4);
    u16*   h1b    = (u16*)  alloc((size_t)MPAD * 512 * 2);
    float* Wh2    = (float*)alloc((size_t)NN * 64 * 4);
    float* fd2    = (float*)alloc((size_t)NN * 4);
    float* fs2    = (float*)alloc((size_t)NN * 4);
    int*   cnt    = (int*)  alloc((size_t)NN * 4);
    int*   startp = (int*)  alloc(((size_t)NN + 1) * 4);
    int*   wr     = (int*)  alloc((size_t)NN * 4);
    int*   ecol   = (int*)  alloc((size_t)EE * 4);

    // ---- CSR build ----
    fill_i32<<<cdiv_l(NN, 256), 256, 0, stream>>>(cnt, 0, (long)NN);
    hist_rows<<<cdiv_l(EE, 256), 256, 0, stream>>>(row, cnt);
    scan_nodes<<<1, 1024, 0, stream>>>(cnt, startp, wr);
    scatter_edges<<<cdiv_l(EE, 256), 256, 0, stream>>>(row, col, wr, ecol);

    // ---- casts / packs ----
    cast_x<<<cdiv_l((long)MPAD * 128, 256), 256, 0, stream>>>(x, xb);
    pack_w1t<<<cdiv_l(512 * 512, 256), 256, 0, stream>>>(W, Wcat_t);
    pack_woutt<<<cdiv_l(64 * 512, 256), 256, 0, stream>>>(W_out, Wot_t);
    // zero h1b pad rows (rows NN..MPAD)
    fill_u16<<<cdiv_l((long)(MPAD - NN) * 512, 256), 256, 0, stream>>>(
        h1b + (size_t)NN * 512, 0, (long)(MPAD - NN) * 512);

    // ---- layer 1 ----
    {
        dim3 grid(512 / 128, cdiv_l(MPAD, 128));
        gemm_bf16<128, true><<<grid, 256, 0, stream>>>(xb, Wcat_t, Whb1, NN, 512, 512);
    }
    dots1<<<cdiv_l((long)NN * 8, 256), 256, 0, stream>>>(Whb1, a, fd1, fs1);
    agg1_csr<<<NN, 512, 0, stream>>>(startp, ecol, fd1, fs1, Whb1, h1b);

    // ---- layer 2 ----
    {
        dim3 grid(1, cdiv_l(MPAD, 128));
        gemm_bf16<64, false><<<grid, 256, 0, stream>>>(h1b, Wot_t, Wh2, NN, 64, 512);
    }
    dots2<<<cdiv_l(NN, 256), 256, 0, stream>>>(Wh2, a_out, fd2, fs2);
    agg2_csr<<<cdiv_l(NN, 4), 256, 0, stream>>>(startp, ecol, fd2, fs2, Wh2, out);
}

// Round 4
// 695.306 us; speedup vs baseline: 4.3618x; 1.3412x over previous
//
#include <hip/hip_runtime.h>
#include <cstdint>
#include <cstddef>

#define NN      50000
#define MPAD    50048   // NN padded to 128
#define EE      800000
#define NFEATC  512
#define NHID    64
#define NHEADS  8
#define HID_TOT 512
#define NCLASS  64
#define ALPHA_LRELU 0.2f

typedef unsigned short u16;
typedef __attribute__((ext_vector_type(8))) unsigned short ushort8;

__device__ __forceinline__ float bf2f(u16 v) {
    return __uint_as_float(((unsigned)v) << 16);
}
__device__ __forceinline__ u16 f2bf(float f) {   // round-to-nearest-even
    unsigned u = __float_as_uint(f);
    return (u16)((u + 0x7fffu + ((u >> 16) & 1u)) >> 16);
}

// -------------------- small utilities --------------------

__global__ void fill_i32(int* __restrict__ p, int v, long n) {
    long i = (long)blockIdx.x * blockDim.x + threadIdx.x;
    if (i < n) p[i] = v;
}
__global__ void fill_u16(u16* __restrict__ p, u16 v, long n) {
    long i = (long)blockIdx.x * blockDim.x + threadIdx.x;
    if (i < n) p[i] = v;
}

// cast x [NN,512] f32 -> xb [MPAD,512] bf16, zero pad rows. 4 elems/thread.
__global__ void cast_x(const float* __restrict__ x, u16* __restrict__ xb) {
    int g = blockIdx.x * 256 + threadIdx.x;
    if (g >= MPAD * 128) return;
    int r = g >> 7;
    int c = (g & 127) * 4;
    u16 o0 = 0, o1 = 0, o2 = 0, o3 = 0;
    if (r < NN) {
        const float4 v = *(const float4*)(x + (size_t)r * 512 + c);
        o0 = f2bf(v.x); o1 = f2bf(v.y); o2 = f2bf(v.z); o3 = f2bf(v.w);
    }
    u16* d = xb + (size_t)r * 512 + c;
    d[0] = o0; d[1] = o1; d[2] = o2; d[3] = o3;
}

// W [8][512][64] f32 -> Wcat_t [512(N=h*64+j)][512(K=f)] bf16 (B^T layout)
__global__ void pack_w1t(const float* __restrict__ W, u16* __restrict__ Wt) {
    int idx = blockIdx.x * 256 + threadIdx.x;
    if (idx >= 512 * 512) return;
    int c = idx >> 9, f = idx & 511;
    int h = c >> 6, j = c & 63;
    Wt[idx] = f2bf(W[(h << 15) + (f << 6) + j]);
}

// W_out [512][64] f32 -> Wot_t [64(N)][512(K)] bf16
__global__ void pack_woutt(const float* __restrict__ W, u16* __restrict__ Wt) {
    int idx = blockIdx.x * 256 + threadIdx.x;
    if (idx >= 64 * 512) return;
    int n = idx >> 9, k = idx & 511;
    Wt[idx] = f2bf(W[k * 64 + n]);
}

// -------------------- CSR build --------------------

__global__ void hist_rows(const int* __restrict__ row, int* __restrict__ cnt) {
    int e = blockIdx.x * 256 + threadIdx.x;
    if (e >= EE) return;
    atomicAdd(&cnt[row[e]], 1);
}

__global__ __launch_bounds__(1024) void scan_nodes(const int* __restrict__ cnt,
                                                   int* __restrict__ start,
                                                   int* __restrict__ wr) {
    __shared__ int part[1024];
    const int tid = threadIdx.x;
    const int CH = (NN + 1023) / 1024;
    const int base = tid * CH;
    int s = 0;
    for (int k = 0; k < CH; k++) {
        int idx = base + k;
        if (idx < NN) s += cnt[idx];
    }
    part[tid] = s;
    __syncthreads();
    for (int off = 1; off < 1024; off <<= 1) {
        int v = part[tid];
        int add = (tid >= off) ? part[tid - off] : 0;
        __syncthreads();
        part[tid] = v + add;
        __syncthreads();
    }
    int excl = (tid == 0) ? 0 : part[tid - 1];
    for (int k = 0; k < CH; k++) {
        int idx = base + k;
        if (idx < NN) {
            start[idx] = excl;
            wr[idx] = excl;
            excl += cnt[idx];
        }
    }
    if (tid == 0) start[NN] = EE;
}

__global__ void scatter_edges(const int* __restrict__ row, const int* __restrict__ col,
                              int* __restrict__ wr, int* __restrict__ ecol) {
    int e = blockIdx.x * 256 + threadIdx.x;
    if (e >= EE) return;
    int i = row[e];
    int pos = atomicAdd(&wr[i], 1);
    ecol[pos] = col[e];
}

// -------------------- bf16 MFMA GEMM --------------------

__device__ __forceinline__ void load_lds_128(const u16* g, u16* l) {
    __builtin_amdgcn_global_load_lds((const __attribute__((address_space(1))) void*)g,
                                     (__attribute__((address_space(3))) void*)l,
                                     16, 0, 0);
}

typedef __attribute__((ext_vector_type(8))) short frag8;
typedef __attribute__((ext_vector_type(4))) float f32x4;

template <int BN, bool OUT_BF16>
__global__ __launch_bounds__(256) void gemm_bf16(const u16* __restrict__ A,
                                                 const u16* __restrict__ Bt,
                                                 void* __restrict__ Cv,
                                                 int M, int N, int K) {
    constexpr int BM = 128, BK = 32;
    constexpr int WN = BN / 2;
    constexpr int NT = WN / 16;
    __shared__ u16 As[BM * BK];
    __shared__ u16 Bs[BN * BK];
    const int tid = threadIdx.x;
    const int wave = tid >> 6, lane = tid & 63;
    const int wm = wave & 1, wn = wave >> 1;
    const int bm = blockIdx.y * BM, bn = blockIdx.x * BN;
    const int q = lane >> 4, lr = lane & 15;

    f32x4 acc[4][NT] = {};

    for (int k0 = 0; k0 < K; k0 += BK) {
        #pragma unroll
        for (int c = wave; c < (BM * BK) / 512; c += 4) {
            int f = c * 512 + lane * 8;
            int row = f >> 5, ck = f & 31;
            load_lds_128(A + (size_t)(bm + row) * K + k0 + ck, As + c * 512);
        }
        #pragma unroll
        for (int c = wave; c < (BN * BK) / 512; c += 4) {
            int f = c * 512 + lane * 8;
            int row = f >> 5, ck = f & 31;
            load_lds_128(Bt + (size_t)(bn + row) * K + k0 + ck, Bs + c * 512);
        }
        __syncthreads();
        frag8 af[4], bfr[NT];
        #pragma unroll
        for (int am = 0; am < 4; am++)
            af[am] = *(const frag8*)(As + (wm * 64 + am * 16 + lr) * 32 + q * 8);
        #pragma unroll
        for (int bt = 0; bt < NT; bt++)
            bfr[bt] = *(const frag8*)(Bs + (wn * WN + bt * 16 + lr) * 32 + q * 8);
        #pragma unroll
        for (int am = 0; am < 4; am++)
            #pragma unroll
            for (int bt = 0; bt < NT; bt++)
                acc[am][bt] = __builtin_amdgcn_mfma_f32_16x16x32_bf16(af[am], bfr[bt], acc[am][bt], 0, 0, 0);
        __syncthreads();
    }

    #pragma unroll
    for (int am = 0; am < 4; am++) {
        #pragma unroll
        for (int reg = 0; reg < 4; reg++) {
            int gr = bm + wm * 64 + am * 16 + q * 4 + reg;
            if (gr < M) {
                #pragma unroll
                for (int bt = 0; bt < NT; bt++) {
                    int gc = bn + wn * WN + bt * 16 + lr;
                    float v = acc[am][bt][reg];
                    if (OUT_BF16) ((u16*)Cv)[(size_t)gr * N + gc] = f2bf(v);
                    else          ((float*)Cv)[(size_t)gr * N + gc] = v;
                }
            }
        }
    }
}

// -------------------- attention dot products --------------------

__global__ void dots1(const u16* __restrict__ Wh, const float* __restrict__ a,
                      float* __restrict__ fd, float* __restrict__ fs) {
    int idx = blockIdx.x * 256 + threadIdx.x;
    if (idx >= NN * NHEADS) return;
    int n = idx >> 3, h = idx & 7;
    const u16* w = Wh + (size_t)n * HID_TOT + h * NHID;
    const float* ad = a + h * 2 * NHID;
    float sd = 0.f, ss = 0.f;
    #pragma unroll
    for (int k = 0; k < NHID; k++) {
        float v = bf2f(w[k]);
        sd += v * ad[k];
        ss += v * ad[NHID + k];
    }
    fd[idx] = sd;
    fs[idx] = ss;
}

__global__ void dots2(const float* __restrict__ Wh2, const float* __restrict__ a_out,
                      float* __restrict__ fd, float* __restrict__ fs) {
    int n = blockIdx.x * 256 + threadIdx.x;
    if (n >= NN) return;
    const float* w = Wh2 + (size_t)n * NCLASS;
    float sd = 0.f, ss = 0.f;
    #pragma unroll
    for (int k = 0; k < NCLASS; k++) {
        float v = w[k];
        sd += v * a_out[k];
        ss += v * a_out[NCLASS + k];
    }
    fd[n] = sd;
    fs[n] = ss;
}

// -------------------- CSR segment-softmax aggregation --------------------
// layer 1, merged heads: one wave per node. lane l: head h=l>>3, dims (l&7)*8.. within head.
// i.e. lane l covers Whb[j][l*8 .. l*8+7]  (since h*64 + (l&7)*8 == l*8).
__global__ __launch_bounds__(256) void agg1_merged(const int* __restrict__ start,
                                                   const int* __restrict__ ecol,
                                                   const float* __restrict__ fd,
                                                   const float* __restrict__ fs,
                                                   const u16* __restrict__ Whb,
                                                   u16* __restrict__ h1b) {
    const int i = blockIdx.x * 4 + (threadIdx.x >> 6);
    if (i >= NN) return;
    const int lane = threadIdx.x & 63;
    const int h = lane >> 3;
    const int sub = lane & 7;
    const int s = start[i], e = start[i + 1];
    const float fdv = fd[i * 8 + h];

    // pass 1: per-head max; 8-lane group strides edges
    float m = -__builtin_huge_valf();
    for (int t = s + sub; t < e; t += 8) {
        int j = ecol[t];
        float v = fdv + fs[j * 8 + h];
        v = v > 0.f ? v : ALPHA_LRELU * v;
        m = fmaxf(m, v);
    }
    m = fmaxf(m, __shfl_xor(m, 1));
    m = fmaxf(m, __shfl_xor(m, 2));
    m = fmaxf(m, __shfl_xor(m, 4));

    // pass 2: serial over edges; lane gathers 8 bf16 (16B) of Whb row
    float acc[8] = {};
    float den = 0.f;
    for (int t = s; t < e; ++t) {
        int j = ecol[t];
        float v = fdv + fs[j * 8 + h];
        v = v > 0.f ? v : ALPHA_LRELU * v;
        float p = __expf(v - m);
        den += p;
        ushort8 w = *(const ushort8*)(Whb + (size_t)j * HID_TOT + lane * 8);
        #pragma unroll
        for (int k = 0; k < 8; k++) acc[k] += p * bf2f(w[k]);
    }
    float rden = 1.0f / fmaxf(den, 1e-16f);
    ushort8 o;
    #pragma unroll
    for (int k = 0; k < 8; k++) {
        float v = acc[k] * rden;
        v = v > 0.f ? v : (__expf(v) - 1.0f);
        o[k] = f2bf(v);
    }
    *(ushort8*)(h1b + (size_t)i * HID_TOT + lane * 8) = o;
}

// layer 2: 4 waves / block, wave = node; lane covers NCLASS
__global__ __launch_bounds__(256) void agg2_csr(const int* __restrict__ start,
                                                const int* __restrict__ ecol,
                                                const float* __restrict__ fd,
                                                const float* __restrict__ fs,
                                                const float* __restrict__ Wh2,
                                                float* __restrict__ out) {
    const int i = blockIdx.x * 4 + (threadIdx.x >> 6);
    if (i >= NN) return;
    const int lane = threadIdx.x & 63;
    const int s = start[i], e = start[i + 1];
    const float fdv = fd[i];

    float m = -__builtin_huge_valf();
    for (int t = s + lane; t < e; t += 64) {
        int j = ecol[t];
        float v = fdv + fs[j];
        v = v > 0.f ? v : ALPHA_LRELU * v;
        m = fmaxf(m, v);
    }
    #pragma unroll
    for (int o = 32; o; o >>= 1) m = fmaxf(m, __shfl_xor(m, o));

    float acc = 0.f, den = 0.f;
    for (int t = s; t < e; ++t) {
        int j = ecol[t];
        float v = fdv + fs[j];
        v = v > 0.f ? v : ALPHA_LRELU * v;
        float p = __expf(v - m);
        den += p;
        acc += p * Wh2[(size_t)j * NCLASS + lane];
    }
    out[(size_t)i * NCLASS + lane] = acc / fmaxf(den, 1e-16f);
}

// -------------------- launch --------------------

static inline int cdiv_l(long a, long b) { return (int)((a + b - 1) / b); }

extern "C" void kernel_launch(void* const* d_in, const int* in_sizes, int n_in,
                              void* d_out, int out_size, void* d_ws, size_t ws_size,
                              hipStream_t stream) {
    const float* x     = (const float*)d_in[0];
    const int*   row   = (const int*)d_in[1];
    const int*   col   = (const int*)d_in[2];
    const float* W     = (const float*)d_in[3];
    const float* a     = (const float*)d_in[4];
    const float* W_out = (const float*)d_in[5];
    const float* a_out = (const float*)d_in[6];
    float* out = (float*)d_out;

    char* wsb = (char*)d_ws;
    size_t off = 0;
    auto alloc = [&](size_t bytes) { char* p = wsb + off; off += (bytes + 255) & ~(size_t)255; return p; };
    u16*   xb     = (u16*)  alloc((size_t)MPAD * 512 * 2);
    u16*   Wcat_t = (u16*)  alloc((size_t)512 * 512 * 2);
    u16*   Wot_t  = (u16*)  alloc((size_t)64 * 512 * 2);
    u16*   Whb1   = (u16*)  alloc((size_t)NN * 512 * 2);
    float* fd1    = (float*)alloc((size_t)NN * 8 * 4);
    float* fs1    = (float*)alloc((size_t)NN * 8 * 4);
    u16*   h1b    = (u16*)  alloc((size_t)MPAD * 512 * 2);
    float* Wh2    = (float*)alloc((size_t)NN * 64 * 4);
    float* fd2    = (float*)alloc((size_t)NN * 4);
    float* fs2    = (float*)alloc((size_t)NN * 4);
    int*   cnt    = (int*)  alloc((size_t)NN * 4);
    int*   startp = (int*)  alloc(((size_t)NN + 1) * 4);
    int*   wr     = (int*)  alloc((size_t)NN * 4);
    int*   ecol   = (int*)  alloc((size_t)EE * 4);

    // ---- CSR build ----
    fill_i32<<<cdiv_l(NN, 256), 256, 0, stream>>>(cnt, 0, (long)NN);
    hist_rows<<<cdiv_l(EE, 256), 256, 0, stream>>>(row, cnt);
    scan_nodes<<<1, 1024, 0, stream>>>(cnt, startp, wr);
    scatter_edges<<<cdiv_l(EE, 256), 256, 0, stream>>>(row, col, wr, ecol);

    // ---- casts / packs ----
    cast_x<<<cdiv_l((long)MPAD * 128, 256), 256, 0, stream>>>(x, xb);
    pack_w1t<<<cdiv_l(512 * 512, 256), 256, 0, stream>>>(W, Wcat_t);
    pack_woutt<<<cdiv_l(64 * 512, 256), 256, 0, stream>>>(W_out, Wot_t);
    fill_u16<<<cdiv_l((long)(MPAD - NN) * 512, 256), 256, 0, stream>>>(
        h1b + (size_t)NN * 512, 0, (long)(MPAD - NN) * 512);

    // ---- layer 1 ----
    {
        dim3 grid(512 / 128, cdiv_l(MPAD, 128));
        gemm_bf16<128, true><<<grid, 256, 0, stream>>>(xb, Wcat_t, Whb1, NN, 512, 512);
    }
    dots1<<<cdiv_l((long)NN * 8, 256), 256, 0, stream>>>(Whb1, a, fd1, fs1);
    agg1_merged<<<cdiv_l(NN, 4), 256, 0, stream>>>(startp, ecol, fd1, fs1, Whb1, h1b);

    // ---- layer 2 ----
    {
        dim3 grid(1, cdiv_l(MPAD, 128));
        gemm_bf16<64, false><<<grid, 256, 0, stream>>>(h1b, Wot_t, Wh2, NN, 64, 512);
    }
    dots2<<<cdiv_l(NN, 256), 256, 0, stream>>>(Wh2, a_out, fd2, fs2);
    agg2_csr<<<cdiv_l(NN, 4), 256, 0, stream>>>(startp, ecol, fd2, fs2, Wh2, out);
}